// Round 19
// baseline (385.975 us; speedup 1.0000x reference)
//
#include <hip/hip_runtime.h>
#include <hip/hip_bf16.h>
#include <math.h>

#define NEG_SLOPE 0.2f
#define N_LAYERS 4

typedef __bf16 bf16_t;
typedef __attribute__((ext_vector_type(8))) __bf16 bf16x8;
typedef __attribute__((ext_vector_type(4))) __bf16 bf16x4;
typedef __attribute__((ext_vector_type(4))) float f32x4;
typedef __attribute__((ext_vector_type(8))) float f32x8;

static __device__ __forceinline__ float leaky(float v){ return v > 0.f ? v : NEG_SLOPE * v; }

static __device__ __forceinline__ bf16x8 relu8(bf16x8 v){
#pragma unroll
  for(int i = 0; i < 8; ++i) v[i] = (v[i] > (bf16_t)0.f) ? v[i] : (bf16_t)0.f;
  return v;
}

// ---------------- CSR build (edge structure fixed across layers) ----------------

__global__ void fill_int_kernel(int* __restrict__ p, int v, int n){
  int i = blockIdx.x*blockDim.x + threadIdx.x;
  if(i < n) p[i] = v;
}

__global__ void hist_kernel(const int* __restrict__ dst, int E, int* __restrict__ deg){
  int e = blockIdx.x*blockDim.x + threadIdx.x;
  if(e < E) atomicAdd(&deg[dst[e]], 1);
}

__global__ void scan_kernel(const int* __restrict__ deg, int* __restrict__ offs, int N){
  __shared__ int wsum[4];
  int t = threadIdx.x, lane = t & 63, w = t >> 6;
  int carry = 0;
  for(int base = 0; base < N; base += 256){
    int v = (base + t < N) ? deg[base + t] : 0;
    int s = v;
#pragma unroll
    for(int o = 1; o < 64; o <<= 1){
      int u = __shfl_up(s, o);
      if(lane >= o) s += u;
    }
    if(lane == 63) wsum[w] = s;
    __syncthreads();
    int woff = 0;
    for(int i = 0; i < w; ++i) woff += wsum[i];
    if(base + t < N) offs[base + t + 1] = carry + woff + s;
    int tot = wsum[0] + wsum[1] + wsum[2] + wsum[3];
    __syncthreads();
    carry += tot;
  }
  if(t == 0) offs[0] = 0;
}

// scatter (blocks [0,SCB)) + per-block degree histogram (blocks [SCB, SCB+NB))
__global__ void scatter_bhist_kernel(const int* __restrict__ src, const int* __restrict__ dst,
                                     const int* __restrict__ rel, int E,
                                     const int* __restrict__ offs, int* __restrict__ cursor,
                                     int* __restrict__ srcs, int* __restrict__ rels,
                                     int N, int* __restrict__ blkhist, int SCB){
  __shared__ int h[256];
  if((int)blockIdx.x < SCB){
    int e = blockIdx.x * 256 + threadIdx.x;
    if(e < E){
      int d = dst[e];
      int pos = offs[d] + atomicAdd(&cursor[d], 1);
      srcs[pos] = src[e];
      rels[pos] = rel[e];
    }
  } else {
    int b = blockIdx.x - SCB;
    int t = threadIdx.x;
    h[t] = 0; __syncthreads();
    int i = b * 256 + t;
    if(i < N){
      int d = offs[i+1] - offs[i]; if(d > 255) d = 255;
      atomicAdd(&h[d], 1);
    }
    __syncthreads();
    blkhist[b * 256 + t] = h[t];
  }
}

__global__ void deg_base_kernel(int* __restrict__ blkhist, int nb){
  __shared__ int tot[256];
  int d = threadIdx.x;
  int s = 0;
  for(int b = 0; b < nb; ++b){
    int v = blkhist[b * 256 + d];
    blkhist[b * 256 + d] = s;
    s += v;
  }
  tot[d] = s; __syncthreads();
  int start = 0;
  for(int k = d + 1; k < 256; ++k) start += tot[k];
  for(int b = 0; b < nb; ++b) blkhist[b * 256 + d] += start;
}

__global__ void deg_place_kernel(const int* __restrict__ offs, int N,
                                 const int* __restrict__ blkhist, int* __restrict__ order){
  __shared__ int cur[256];
  int t = threadIdx.x;
  cur[t] = blkhist[blockIdx.x * 256 + t];
  __syncthreads();
  int i = blockIdx.x * 256 + t;
  if(i < N){
    int d = offs[i+1] - offs[i]; if(d > 255) d = 255;
    int pos = atomicAdd(&cur[d], 1);
    order[pos] = i;
  }
}

// ---------------- batched weight transpose + bf16 hi/lo split ----

__global__ void transpose_split_all_kernel(
    const float* __restrict__ Wl, const float* __restrict__ Wr,
    const float* __restrict__ We, const float* __restrict__ Wb,
    bf16_t* __restrict__ tWlh, bf16_t* __restrict__ tWll,
    bf16_t* __restrict__ tWrh, bf16_t* __restrict__ tWrl,
    bf16_t* __restrict__ tWeh, bf16_t* __restrict__ tWel,
    bf16_t* __restrict__ tWbh, bf16_t* __restrict__ tWbl){
  __shared__ float t[32][33];
  const int z = blockIdx.z, type = z >> 2, layer = z & 3;
  const int K  = (type < 3) ? 128 : 1024;
  const int Nn = (type < 3) ? 1024 : 128;
  const float* W; bf16_t* Th; bf16_t* Tl;
  if(type == 0){ W = Wl; Th = tWlh; Tl = tWll; }
  else if(type == 1){ W = Wr; Th = tWrh; Tl = tWrl; }
  else if(type == 2){ W = We; Th = tWeh; Tl = tWel; }
  else { W = Wb; Th = tWbh; Tl = tWbl; }
  size_t wo = (size_t)layer * 131072;
  W += wo; Th += wo; Tl += wo;
  const int nbx = K / 32;
  const int bx = blockIdx.x % nbx, by = blockIdx.x / nbx;
  const int k0 = bx * 32, n0 = by * 32;
  const int tx = threadIdx.x, ty = threadIdx.y;
#pragma unroll
  for(int i = 0; i < 4; ++i)
    t[ty*4 + i][tx] = W[(size_t)(k0 + ty*4 + i) * Nn + n0 + tx];
  __syncthreads();
#pragma unroll
  for(int i = 0; i < 4; ++i){
    int n = ty*4 + i;
    float v = t[tx][n];
    bf16_t h = (bf16_t)v;
    bf16_t l = (bf16_t)(v - (float)h);
    Th[(size_t)(n0 + n) * K + k0 + tx] = h;
    Tl[(size_t)(n0 + n) * K + k0 + tx] = l;
  }
}

// ---------------- merged projection GEMM: 2-MFMA form Ah*(Bh+Bl) ----------------

__global__ __launch_bounds__(256, 3) void gemm_proj_kernel(
    const float* __restrict__ Ar, const float* __restrict__ Ax,
    const bf16_t* __restrict__ Axb,
    const bf16_t* __restrict__ Weh, const bf16_t* __restrict__ Wel,
    const bf16_t* __restrict__ Wlh, const bf16_t* __restrict__ Wll,
    const bf16_t* __restrict__ Wrh, const bf16_t* __restrict__ Wrl,
    const float* __restrict__ biasL, const float* __restrict__ biasR,
    const float* __restrict__ biasB, float* __restrict__ ro,
    bf16_t* __restrict__ rpb, bf16_t* __restrict__ xlb, bf16_t* __restrict__ xrb,
    int R, int Nn, int rjobs, int xjobs, int bjobs){
  constexpr int LDA  = 136;
  constexpr int LDBB = 72;
  __shared__ char smem[53248];
  bf16_t* Ah  = (bf16_t*)smem;               // 34816
  bf16_t* Bhl = (bf16_t*)(smem + 34816);     // 18432

  const int tid  = threadIdx.x;
  const int lane = tid & 63;
  const int wid  = tid >> 6;
  const int wm = wid >> 1, wn = wid & 1;
  const int l15 = lane & 15;
  const int kb  = (lane >> 4) * 8;

  int nwg = gridDim.x;
  int lin = blockIdx.x;
  int w = ((nwg & 7) == 0) ? ((lin & 7) * (nwg >> 3) + (lin >> 3)) : lin;
  int job, jw;
  if(w < rjobs){ job = 0; jw = w; }
  else if(w < rjobs + xjobs){ job = 1; jw = w - rjobs; }
  else if(w < rjobs + 2 * xjobs){ job = 2; jw = w - rjobs - xjobs; }
  else { job = 3; jw = w - rjobs - 2 * xjobs; }

  if(job == 3){
    int idx8 = (jw * 256 + tid) * 8;
    if(idx8 < R * 128){
      const float* bp = biasB + (idx8 & 127);
      *(float4*)(ro + idx8)     = *(const float4*)bp;
      *(float4*)(ro + idx8 + 4) = *(const float4*)(bp + 4);
    }
    return;
  }

  const float*  A   = (job == 0) ? Ar : Ax;
  const bf16_t* Bth = (job == 0) ? Weh : (job == 1) ? Wlh : Wrh;
  const bf16_t* Btl = (job == 0) ? Wel : (job == 1) ? Wll : Wrl;
  const int M = (job == 0) ? R : Nn;
  const int row0 = (jw >> 3) * 128, col0 = (jw & 7) * 128;
  const bool abf = (job != 0) && (Axb != nullptr);

  const int ns0 = tid >> 2,        kq0 = tid & 3;
  const int ns1 = (tid + 256) >> 2, kq1 = (tid + 256) & 3;
  const size_t gb0 = (size_t)(col0 + ns0) * 128 + kq0 * 8;
  const size_t gb1 = (size_t)(col0 + ns1) * 128 + kq1 * 8;
  const int lo0 = ns0 * LDBB + kq0 * 8;
  const int lo1 = ns1 * LDBB + kq1 * 8;

  // ---- stage A once (full K=128) ----
  if(abf){
#pragma unroll
    for(int i = 0; i < 8; ++i){
      int f = tid + i * 256;
      int r = f >> 4, kq = f & 15;
      bf16x8 v = {};
      if(row0 + r < M) v = *(const bf16x8*)(Axb + (size_t)(row0 + r) * 128 + kq * 8);
      *(bf16x8*)&Ah[r * LDA + kq * 8] = v;
    }
  } else {
#pragma unroll
    for(int i = 0; i < 16; ++i){
      int f = tid + i * 256;
      int r = f >> 5, kq = f & 31;
      float4 v = make_float4(0.f, 0.f, 0.f, 0.f);
      if(row0 + r < M) v = *(const float4*)(A + (size_t)(row0 + r) * 128 + kq * 4);
      bf16x4 hv = (bf16x4){(bf16_t)v.x, (bf16_t)v.y, (bf16_t)v.z, (bf16_t)v.w};
      *(bf16x4*)&Ah[r * LDA + kq * 4] = hv;
    }
  }
  // ---- stage B for k0 = 0 ----
  {
    bf16x8 h0 = *(const bf16x8*)(Bth + gb0);
    bf16x8 l0v = *(const bf16x8*)(Btl + gb0);
    bf16x8 h1 = *(const bf16x8*)(Bth + gb1);
    bf16x8 l1v = *(const bf16x8*)(Btl + gb1);
    *(bf16x8*)&Bhl[lo0]      = h0;
    *(bf16x8*)&Bhl[lo0 + 32] = l0v;
    *(bf16x8*)&Bhl[lo1]      = h1;
    *(bf16x8*)&Bhl[lo1 + 32] = l1v;
  }
  __syncthreads();

  f32x4 acc[4][4];
#pragma unroll
  for(int m = 0; m < 4; ++m)
#pragma unroll
    for(int n = 0; n < 4; ++n) acc[m][n] = (f32x4){0.f, 0.f, 0.f, 0.f};

  bf16x8 sb_h0, sb_l0, sb_h1, sb_l1;

#pragma unroll
  for(int step = 0; step < 4; ++step){
    const int k0 = step * 32;
    if(step < 3){
      sb_h0 = *(const bf16x8*)(Bth + gb0 + k0 + 32);
      sb_l0 = *(const bf16x8*)(Btl + gb0 + k0 + 32);
      sb_h1 = *(const bf16x8*)(Bth + gb1 + k0 + 32);
      sb_l1 = *(const bf16x8*)(Btl + gb1 + k0 + 32);
    }
    bf16x8 ah[4], bh[4], bl[4];
#pragma unroll
    for(int m = 0; m < 4; ++m){
      int r = wm * 64 + m * 16 + l15;
      ah[m] = *(bf16x8*)&Ah[r * LDA + k0 + kb];
    }
#pragma unroll
    for(int n = 0; n < 4; ++n){
      int c = wn * 64 + n * 16 + l15;
      bh[n] = *(bf16x8*)&Bhl[c * LDBB + kb];
      bl[n] = *(bf16x8*)&Bhl[c * LDBB + 32 + kb];
    }
#pragma unroll
    for(int m = 0; m < 4; ++m)
#pragma unroll
      for(int n = 0; n < 4; ++n){
        acc[m][n] = __builtin_amdgcn_mfma_f32_16x16x32_bf16(ah[m], bh[n], acc[m][n], 0, 0, 0);
        acc[m][n] = __builtin_amdgcn_mfma_f32_16x16x32_bf16(ah[m], bl[n], acc[m][n], 0, 0, 0);
      }
    if(step < 3){
      __syncthreads();
      *(bf16x8*)&Bhl[lo0]      = sb_h0;
      *(bf16x8*)&Bhl[lo0 + 32] = sb_l0;
      *(bf16x8*)&Bhl[lo1]      = sb_h1;
      *(bf16x8*)&Bhl[lo1 + 32] = sb_l1;
      __syncthreads();
    }
  }

  const float* biasP = (job == 0) ? nullptr : (job == 1) ? biasL : biasR;
  bf16_t* dst = (job == 0) ? rpb : (job == 1) ? xlb : xrb;
  bf16_t* tile = Ah;
  __syncthreads();
#pragma unroll
  for(int n = 0; n < 4; ++n){
    int col = wn * 64 + n * 16 + l15;
    float bv = biasP ? biasP[col0 + col] : 0.f;
#pragma unroll
    for(int m = 0; m < 4; ++m){
      int rb = wm * 64 + m * 16 + (lane >> 4) * 4;
#pragma unroll
      for(int r = 0; r < 4; ++r)
        tile[(rb + r) * 136 + col] = (bf16_t)(acc[m][n][r] + bv);
    }
  }
  __syncthreads();
#pragma unroll
  for(int i = 0; i < 8; ++i){
    int ei = i * 2048 + tid * 8;
    int rr = ei >> 7, cc = ei & 127;
    if(row0 + rr < M)
      *(bf16x8*)(dst + (size_t)(row0 + rr) * 1024 + col0 + cc) = *(bf16x8*)&tile[rr * 136 + cc];
  }
}

// ---------------- relation update GEMM: ro += relu(rpb) @ Wb (split-K 16, 2-MFMA) -------

__global__ __launch_bounds__(256) void gemm_rel_kernel(
    const bf16_t* __restrict__ Ag,
    const bf16_t* __restrict__ Bth, const bf16_t* __restrict__ Btl,
    float* __restrict__ C, int M){
  constexpr int LDK = 40;
  __shared__ bf16_t Ah[128 * LDK];
  __shared__ bf16_t Bh[128 * LDK];
  __shared__ bf16_t Bl[128 * LDK];

  const int tid  = threadIdx.x;
  const int lane = tid & 63;
  const int wid  = tid >> 6;
  const int wm = wid >> 1, wn = wid & 1;
  const int row0 = blockIdx.y * 128;
  const int l15 = lane & 15;
  const int kb  = (lane >> 4) * 8;
  const int kbeg = blockIdx.z * 64;

  f32x4 acc[4][4];
#pragma unroll
  for(int m = 0; m < 4; ++m)
#pragma unroll
    for(int n = 0; n < 4; ++n) acc[m][n] = (f32x4){0.f, 0.f, 0.f, 0.f};

#pragma unroll
  for(int tt = 0; tt < 2; ++tt){
    int k0 = kbeg + tt * 32;
    __syncthreads();
#pragma unroll
    for(int i = 0; i < 2; ++i){
      int f = tid + i * 256;
      int r = f >> 2, kq = f & 3;
      bf16x8 vh = {};
      if(row0 + r < M)
        vh = relu8(*(const bf16x8*)(Ag + (size_t)(row0 + r) * 1024 + k0 + kq * 8));
      *(bf16x8*)&Ah[r * LDK + kq * 8] = vh;
      size_t gb = (size_t)r * 1024 + k0 + kq * 8;
      *(bf16x8*)&Bh[r * LDK + kq * 8] = *(const bf16x8*)(Bth + gb);
      *(bf16x8*)&Bl[r * LDK + kq * 8] = *(const bf16x8*)(Btl + gb);
    }
    __syncthreads();

    bf16x8 ah[4], bh[4], bl[4];
#pragma unroll
    for(int m = 0; m < 4; ++m){
      int r = wm * 64 + m * 16 + l15;
      ah[m] = *(bf16x8*)&Ah[r * LDK + kb];
    }
#pragma unroll
    for(int n = 0; n < 4; ++n){
      int c = wn * 64 + n * 16 + l15;
      bh[n] = *(bf16x8*)&Bh[c * LDK + kb];
      bl[n] = *(bf16x8*)&Bl[c * LDK + kb];
    }
#pragma unroll
    for(int m = 0; m < 4; ++m)
#pragma unroll
      for(int n = 0; n < 4; ++n){
        acc[m][n] = __builtin_amdgcn_mfma_f32_16x16x32_bf16(ah[m], bh[n], acc[m][n], 0, 0, 0);
        acc[m][n] = __builtin_amdgcn_mfma_f32_16x16x32_bf16(ah[m], bl[n], acc[m][n], 0, 0, 0);
      }
  }

#pragma unroll
  for(int n = 0; n < 4; ++n){
    int col = wn * 64 + n * 16 + l15;
    if(col < 128){
#pragma unroll
      for(int m = 0; m < 4; ++m){
        int rbase = row0 + wm * 64 + m * 16 + (lane >> 4) * 4;
#pragma unroll
        for(int r = 0; r < 4; ++r){
          if(rbase + r < M)
            atomicAdd(&C[(size_t)(rbase + r) * 128 + col], acc[m][n][r]);
        }
      }
    }
  }
}

// ---------------- fused node kernel: FOUR waves per node (2 heads/wave) --------------
// Per-wave state halves (f32x4 accumulators, bf16x4 operands) -> lower VGPR, higher
// occupancy; 2x wave count for latency hiding. Head h's 128 cols live entirely in one
// 32-lane group (32 lanes x 4 elems), so softmax m/den stay lane-group-local.

__global__ __launch_bounds__(256) void node_fused_kernel(
    const bf16_t* __restrict__ xlb, const bf16_t* __restrict__ xrb,
    const bf16_t* __restrict__ rpb,
    const int* __restrict__ offs, const int* __restrict__ srcs, const int* __restrict__ rels,
    const int* __restrict__ order,
    const float* __restrict__ att, const float* __restrict__ bias,
    float* __restrict__ xout, bf16_t* __restrict__ xq, int N){
  __shared__ float tsh[4][128];
  const int wid  = threadIdx.x >> 6;       // 0..3
  const int lane = threadIdx.x & 63;
  const int node = order[blockIdx.x];      // grid == N
  const int beg = offs[node], end = offs[node + 1];
  const float inv = 1.0f / fmaxf((float)(end - beg), 1.0f);

  const int o  = wid * 256 + lane * 4;     // elem offset in 1024-elem row
  const int h  = wid * 2 + (lane >> 5);
  const int c0 = (lane & 31) * 4;
  f32x4 av = *(const f32x4*)(att + h * 128 + c0);
  bf16x4 xrv = *(const bf16x4*)(xrb + (size_t)node * 1024 + o);
  f32x4 xr;
#pragma unroll
  for(int i = 0; i < 4; ++i) xr[i] = (float)xrv[i];

  f32x4 lac = (f32x4){0.f,0.f,0.f,0.f};
  f32x4 num = (f32x4){0.f,0.f,0.f,0.f};
  float m = -INFINITY, den = 0.f;

  // preload first iteration's indices (software prefetch pipeline)
  int p = beg;
  int cs0 = 0, cs1 = 0, cs2 = 0, cs3 = 0, cr0 = 0, cr1 = 0, cr2 = 0, cr3 = 0;
  float k1 = 0.f, k2 = 0.f, k3 = 0.f;
  if(p < end){
    int rem = end - p;
    int i1 = (rem > 1) ? p + 1 : p;
    int i2 = (rem > 2) ? p + 2 : p;
    int i3 = (rem > 3) ? p + 3 : p;
    k1 = (rem > 1) ? 1.f : 0.f;
    k2 = (rem > 2) ? 1.f : 0.f;
    k3 = (rem > 3) ? 1.f : 0.f;
    cs0 = srcs[p];  cr0 = rels[p];
    cs1 = srcs[i1]; cr1 = rels[i1];
    cs2 = srcs[i2]; cr2 = rels[i2];
    cs3 = srcs[i3]; cr3 = rels[i3];
  }

  while(p < end){
    bf16x4 a0 = *(const bf16x4*)(xlb + (size_t)cs0 * 1024 + o);
    bf16x4 b0 = *(const bf16x4*)(rpb + (size_t)cr0 * 1024 + o);
    bf16x4 a1 = *(const bf16x4*)(xlb + (size_t)cs1 * 1024 + o);
    bf16x4 b1 = *(const bf16x4*)(rpb + (size_t)cr1 * 1024 + o);
    bf16x4 a2 = *(const bf16x4*)(xlb + (size_t)cs2 * 1024 + o);
    bf16x4 b2 = *(const bf16x4*)(rpb + (size_t)cr2 * 1024 + o);
    bf16x4 a3 = *(const bf16x4*)(xlb + (size_t)cs3 * 1024 + o);
    bf16x4 b3 = *(const bf16x4*)(rpb + (size_t)cr3 * 1024 + o);

    int np = p + 4;
    int ns0 = 0, ns1 = 0, ns2 = 0, ns3 = 0, nr0 = 0, nr1 = 0, nr2 = 0, nr3 = 0;
    float nk1 = 0.f, nk2 = 0.f, nk3 = 0.f;
    if(np < end){
      int rem = end - np;
      int i1 = (rem > 1) ? np + 1 : np;
      int i2 = (rem > 2) ? np + 2 : np;
      int i3 = (rem > 3) ? np + 3 : np;
      nk1 = (rem > 1) ? 1.f : 0.f;
      nk2 = (rem > 2) ? 1.f : 0.f;
      nk3 = (rem > 3) ? 1.f : 0.f;
      ns0 = srcs[np]; nr0 = rels[np];
      ns1 = srcs[i1]; nr1 = rels[i1];
      ns2 = srcs[i2]; nr2 = rels[i2];
      ns3 = srcs[i3]; nr3 = rels[i3];
    }

    float l0 = 0.f, l1 = 0.f, l2 = 0.f, l3 = 0.f;
#pragma unroll
    for(int i = 0; i < 4; ++i){
      float v0 = (float)b0[i], v1 = (float)b1[i], v2 = (float)b2[i], v3 = (float)b3[i];
      lac[i] += v0 + k1 * v1 + k2 * v2 + k3 * v3;
      l0 += leaky((float)a0[i] + xr[i] + v0) * av[i];
      l1 += leaky((float)a1[i] + xr[i] + v1) * av[i];
      l2 += leaky((float)a2[i] + xr[i] + v2) * av[i];
      l3 += leaky((float)a3[i] + xr[i] + v3) * av[i];
    }
#pragma unroll
    for(int q = 16; q >= 1; q >>= 1){
      l0 += __shfl_xor(l0, q); l1 += __shfl_xor(l1, q);
      l2 += __shfl_xor(l2, q); l3 += __shfl_xor(l3, q);
    }
    l1 = (k1 > 0.f) ? l1 : -INFINITY;
    l2 = (k2 > 0.f) ? l2 : -INFINITY;
    l3 = (k3 > 0.f) ? l3 : -INFINITY;
    float nm = fmaxf(m, fmaxf(fmaxf(l0, l1), fmaxf(l2, l3)));
    float sc = __expf(m - nm);
    float w0 = __expf(l0 - nm), w1 = __expf(l1 - nm);
    float w2 = __expf(l2 - nm), w3 = __expf(l3 - nm);
    den = den * sc + w0 + w1 + w2 + w3;
#pragma unroll
    for(int i = 0; i < 4; ++i)
      num[i] = num[i] * sc + w0 * (float)a0[i] + w1 * (float)a1[i]
                           + w2 * (float)a2[i] + w3 * (float)a3[i];
    m = nm;

    p = np;
    cs0 = ns0; cs1 = ns1; cs2 = ns2; cs3 = ns3;
    cr0 = nr0; cr1 = nr1; cr2 = nr2; cr3 = nr3;
    k1 = nk1; k2 = nk2; k3 = nk3;
  }

  // self loop: edge_attr = mean of incoming rproj; self message = own xl row
  bf16x4 xlv = *(const bf16x4*)(xlb + (size_t)node * 1024 + o);
  float sl = 0.f;
#pragma unroll
  for(int i = 0; i < 4; ++i)
    sl += leaky((float)xlv[i] + xr[i] + lac[i] * inv) * av[i];
#pragma unroll
  for(int q = 16; q >= 1; q >>= 1) sl += __shfl_xor(sl, q);
  {
    float nm = fmaxf(m, sl);
    float sc = __expf(m - nm), wv = __expf(sl - nm);
    den = den * sc + wv;
#pragma unroll
    for(int i = 0; i < 4; ++i) num[i] = num[i] * sc + wv * (float)xlv[i];
    m = nm;
  }

  // per-head normalize; combine the wave's two heads (lane ^ 32), then 4-wave LDS sum
  f32x4 t;
  float d = 1.0f / den;
#pragma unroll
  for(int i = 0; i < 4; ++i) t[i] = num[i] * d;
#pragma unroll
  for(int i = 0; i < 4; ++i) t[i] += __shfl_xor(t[i], 32);

  if(lane < 32){
#pragma unroll
    for(int i = 0; i < 4; ++i) tsh[wid][lane * 4 + i] = t[i];
  }
  __syncthreads();
  if(wid == 0 && lane < 32){
    const float* bp = bias + lane * 4;
    float q[4];
#pragma unroll
    for(int i = 0; i < 4; ++i){
      int c = lane * 4 + i;
      q[i] = (tsh[0][c] + tsh[1][c] + tsh[2][c] + tsh[3][c]) * 0.125f + bp[i];
    }
    bf16x4 qb;
#pragma unroll
    for(int i = 0; i < 4; ++i) qb[i] = (bf16_t)q[i];
    *(bf16x4*)(xq + (size_t)node * 128 + lane * 4) = qb;
    if(xout){
      *(float4*)(xout + (size_t)node * 128 + lane * 4) = make_float4(q[0], q[1], q[2], q[3]);
    }
  }
}

// ---------------- launch ----------------

extern "C" void kernel_launch(void* const* d_in, const int* in_sizes, int n_in,
                              void* d_out, int out_size, void* d_ws, size_t ws_size,
                              hipStream_t stream){
  const float* x0   = (const float*)d_in[0];
  const int*   ei   = (const int*)d_in[1];
  const float* rel0 = (const float*)d_in[2];
  const int*   ridx = (const int*)d_in[3];
  const float* Wl   = (const float*)d_in[4];
  const float* bl   = (const float*)d_in[5];
  const float* Wr   = (const float*)d_in[6];
  const float* br   = (const float*)d_in[7];
  const float* We   = (const float*)d_in[8];
  const float* att  = (const float*)d_in[9];
  const float* bias = (const float*)d_in[10];
  const float* Wb   = (const float*)d_in[11];
  const float* bb   = (const float*)d_in[12];

  const int D = 128, HC = 1024;
  const int N = in_sizes[0] / D;
  const int E = in_sizes[1] / 2;
  const int R = in_sizes[2] / D;
  const int WSZ = D * HC;
  const int NB = (N + 255) / 256;
  const int SCB = (E + 255) / 256;

  const int* src = ei;
  const int* dst = ei + E;

  char* ws = (char*)d_ws;
  size_t off = 0;
  auto alloc = [&](size_t bytes) -> void* {
    void* p = ws + off;
    off += (bytes + 255) & ~(size_t)255;
    return p;
  };
  bf16_t* xlb    = (bf16_t*)alloc((size_t)N * HC * 2);
  bf16_t* xrb    = (bf16_t*)alloc((size_t)N * HC * 2);
  bf16_t* rpb    = (bf16_t*)alloc((size_t)R * HC * 2);
  bf16_t* xqA    = (bf16_t*)alloc((size_t)N * D * 2);
  bf16_t* xqB    = (bf16_t*)alloc((size_t)N * D * 2);
  float*  rbufA  = (float*)alloc((size_t)R * D * 4);
  float*  rbufB  = (float*)alloc((size_t)R * D * 4);
  int* zbase   = (int*)alloc((size_t)(2 * N) * 4);
  int* deg     = zbase;
  int* cursor  = zbase + N;
  int* offs    = (int*)alloc((size_t)(N + 1) * 4);
  int* blkhist = (int*)alloc((size_t)NB * 256 * 4);
  int* order   = (int*)alloc((size_t)N * 4);
  int* srcs    = (int*)alloc((size_t)E * 4);
  int* rels    = (int*)alloc((size_t)E * 4);
  bf16_t* tWl_h = (bf16_t*)alloc((size_t)N_LAYERS * WSZ * 2);
  bf16_t* tWl_l = (bf16_t*)alloc((size_t)N_LAYERS * WSZ * 2);
  bf16_t* tWr_h = (bf16_t*)alloc((size_t)N_LAYERS * WSZ * 2);
  bf16_t* tWr_l = (bf16_t*)alloc((size_t)N_LAYERS * WSZ * 2);
  bf16_t* tWe_h = (bf16_t*)alloc((size_t)N_LAYERS * WSZ * 2);
  bf16_t* tWe_l = (bf16_t*)alloc((size_t)N_LAYERS * WSZ * 2);
  bf16_t* tWb_h = (bf16_t*)alloc((size_t)N_LAYERS * WSZ * 2);
  bf16_t* tWb_l = (bf16_t*)alloc((size_t)N_LAYERS * WSZ * 2);
  bf16_t* xq[2] = {xqA, xqB};
  float* rbuf[2] = {rbufA, rbufB};

  float* out_x = (float*)d_out;
  float* out_r = (float*)d_out + (size_t)N * D;

  // CSR build + degree-descending order
  fill_int_kernel<<<(2 * N + 255) / 256, 256, 0, stream>>>(zbase, 0, 2 * N);
  hist_kernel<<<(E + 255) / 256, 256, 0, stream>>>(dst, E, deg);
  scan_kernel<<<1, 256, 0, stream>>>(deg, offs, N);
  scatter_bhist_kernel<<<SCB + NB, 256, 0, stream>>>(
      src, dst, ridx, E, offs, cursor, srcs, rels, N, blkhist, SCB);
  deg_base_kernel<<<1, 256, 0, stream>>>(blkhist, NB);
  deg_place_kernel<<<NB, 256, 0, stream>>>(offs, N, blkhist, order);

  // weight prep: all 16 transpose+splits in ONE dispatch
  transpose_split_all_kernel<<<dim3(128, 1, 16), dim3(32, 8), 0, stream>>>(
      Wl, Wr, We, Wb, tWl_h, tWl_l, tWr_h, tWr_l, tWe_h, tWe_l, tWb_h, tWb_l);

  const int rjobs = ((R + 127) / 128) * (HC / 128);
  const int xjobs = ((N + 127) / 128) * (HC / 128);
  const int bjobs = 128;
  const int nwg = rjobs + 2 * xjobs + bjobs;   // 1520, %8 == 0

  for(int l = 0; l < N_LAYERS; ++l){
    const bf16_t* xq_in = (l == 0) ? nullptr : xq[(l + 1) & 1];
    bf16_t*       xq_out = xq[l & 1];
    float*        xo  = (l == N_LAYERS - 1) ? out_x : nullptr;
    const float*  rin = (l == 0) ? rel0 : rbuf[(l + 1) & 1];
    float*        ro  = (l == N_LAYERS - 1) ? out_r : rbuf[l & 1];
    size_t wo = (size_t)l * WSZ;
    const float* bl_l  = bl + (size_t)l * HC;
    const float* br_l  = br + (size_t)l * HC;
    const float* att_l = att + (size_t)l * 8 * 128;
    const float* bias_l= bias + (size_t)l * D;
    const float* bb_l  = bb + (size_t)l * D;

    // merged projections + bias prefill (2-MFMA; A-once + B-stage split)
    gemm_proj_kernel<<<nwg, 256, 0, stream>>>(
        rin, x0, xq_in, tWe_h + wo, tWe_l + wo, tWl_h + wo, tWl_l + wo, tWr_h + wo, tWr_l + wo,
        bl_l, br_l, bb_l, ro, rpb, xlb, xrb, R, N, rjobs, xjobs, bjobs);
    // fused node pass: 4 waves/node (low-VGPR, high-occupancy)
    node_fused_kernel<<<N, 256, 0, stream>>>(
        xlb, xrb, rpb, offs, srcs, rels, order, att_l, bias_l, xo, xq_out, N);
    // relation update: ro += relu(rpb) @ Wb, split-K 16
    gemm_rel_kernel<<<dim3(1, (R + 127) / 128, 16), 256, 0, stream>>>(
        rpb, tWb_h + wo, tWb_l + wo, ro, R);
  }
}

// Round 20
// 373.859 us; speedup vs baseline: 1.0324x; 1.0324x over previous
//
#include <hip/hip_runtime.h>
#include <hip/hip_bf16.h>
#include <math.h>

#define NEG_SLOPE 0.2f
#define N_LAYERS 4

typedef __bf16 bf16_t;
typedef __attribute__((ext_vector_type(8))) __bf16 bf16x8;
typedef __attribute__((ext_vector_type(4))) __bf16 bf16x4;
typedef __attribute__((ext_vector_type(4))) float f32x4;
typedef __attribute__((ext_vector_type(8))) float f32x8;

// leaky_relu with slope in (0,1): max(v, s*v) is exact for both signs
static __device__ __forceinline__ float leaky(float v){ return fmaxf(v, NEG_SLOPE * v); }

static __device__ __forceinline__ bf16x8 relu8(bf16x8 v){
#pragma unroll
  for(int i = 0; i < 8; ++i) v[i] = (v[i] > (bf16_t)0.f) ? v[i] : (bf16_t)0.f;
  return v;
}

// ---------------- CSR build (edge structure fixed across layers) ----------------

__global__ void fill_int_kernel(int* __restrict__ p, int v, int n){
  int i = blockIdx.x*blockDim.x + threadIdx.x;
  if(i < n) p[i] = v;
}

__global__ void hist_kernel(const int* __restrict__ dst, int E, int* __restrict__ deg){
  int e = blockIdx.x*blockDim.x + threadIdx.x;
  if(e < E) atomicAdd(&deg[dst[e]], 1);
}

__global__ void scan_kernel(const int* __restrict__ deg, int* __restrict__ offs, int N){
  __shared__ int wsum[4];
  int t = threadIdx.x, lane = t & 63, w = t >> 6;
  int carry = 0;
  for(int base = 0; base < N; base += 256){
    int v = (base + t < N) ? deg[base + t] : 0;
    int s = v;
#pragma unroll
    for(int o = 1; o < 64; o <<= 1){
      int u = __shfl_up(s, o);
      if(lane >= o) s += u;
    }
    if(lane == 63) wsum[w] = s;
    __syncthreads();
    int woff = 0;
    for(int i = 0; i < w; ++i) woff += wsum[i];
    if(base + t < N) offs[base + t + 1] = carry + woff + s;
    int tot = wsum[0] + wsum[1] + wsum[2] + wsum[3];
    __syncthreads();
    carry += tot;
  }
  if(t == 0) offs[0] = 0;
}

// scatter (blocks [0,SCB)) + per-block degree histogram (blocks [SCB, SCB+NB))
__global__ void scatter_bhist_kernel(const int* __restrict__ src, const int* __restrict__ dst,
                                     const int* __restrict__ rel, int E,
                                     const int* __restrict__ offs, int* __restrict__ cursor,
                                     int* __restrict__ srcs, int* __restrict__ rels,
                                     int N, int* __restrict__ blkhist, int SCB){
  __shared__ int h[256];
  if((int)blockIdx.x < SCB){
    int e = blockIdx.x * 256 + threadIdx.x;
    if(e < E){
      int d = dst[e];
      int pos = offs[d] + atomicAdd(&cursor[d], 1);
      srcs[pos] = src[e];
      rels[pos] = rel[e];
    }
  } else {
    int b = blockIdx.x - SCB;
    int t = threadIdx.x;
    h[t] = 0; __syncthreads();
    int i = b * 256 + t;
    if(i < N){
      int d = offs[i+1] - offs[i]; if(d > 255) d = 255;
      atomicAdd(&h[d], 1);
    }
    __syncthreads();
    blkhist[b * 256 + t] = h[t];
  }
}

__global__ void deg_base_kernel(int* __restrict__ blkhist, int nb){
  __shared__ int tot[256];
  int d = threadIdx.x;
  int s = 0;
  for(int b = 0; b < nb; ++b){
    int v = blkhist[b * 256 + d];
    blkhist[b * 256 + d] = s;
    s += v;
  }
  tot[d] = s; __syncthreads();
  int start = 0;
  for(int k = d + 1; k < 256; ++k) start += tot[k];
  for(int b = 0; b < nb; ++b) blkhist[b * 256 + d] += start;
}

__global__ void deg_place_kernel(const int* __restrict__ offs, int N,
                                 const int* __restrict__ blkhist, int* __restrict__ order){
  __shared__ int cur[256];
  int t = threadIdx.x;
  cur[t] = blkhist[blockIdx.x * 256 + t];
  __syncthreads();
  int i = blockIdx.x * 256 + t;
  if(i < N){
    int d = offs[i+1] - offs[i]; if(d > 255) d = 255;
    int pos = atomicAdd(&cur[d], 1);
    order[pos] = i;
  }
}

// ---------------- batched weight transpose + bf16 hi/lo split ----

__global__ void transpose_split_all_kernel(
    const float* __restrict__ Wl, const float* __restrict__ Wr,
    const float* __restrict__ We, const float* __restrict__ Wb,
    bf16_t* __restrict__ tWlh, bf16_t* __restrict__ tWll,
    bf16_t* __restrict__ tWrh, bf16_t* __restrict__ tWrl,
    bf16_t* __restrict__ tWeh, bf16_t* __restrict__ tWel,
    bf16_t* __restrict__ tWbh, bf16_t* __restrict__ tWbl){
  __shared__ float t[32][33];
  const int z = blockIdx.z, type = z >> 2, layer = z & 3;
  const int K  = (type < 3) ? 128 : 1024;
  const int Nn = (type < 3) ? 1024 : 128;
  const float* W; bf16_t* Th; bf16_t* Tl;
  if(type == 0){ W = Wl; Th = tWlh; Tl = tWll; }
  else if(type == 1){ W = Wr; Th = tWrh; Tl = tWrl; }
  else if(type == 2){ W = We; Th = tWeh; Tl = tWel; }
  else { W = Wb; Th = tWbh; Tl = tWbl; }
  size_t wo = (size_t)layer * 131072;
  W += wo; Th += wo; Tl += wo;
  const int nbx = K / 32;
  const int bx = blockIdx.x % nbx, by = blockIdx.x / nbx;
  const int k0 = bx * 32, n0 = by * 32;
  const int tx = threadIdx.x, ty = threadIdx.y;
#pragma unroll
  for(int i = 0; i < 4; ++i)
    t[ty*4 + i][tx] = W[(size_t)(k0 + ty*4 + i) * Nn + n0 + tx];
  __syncthreads();
#pragma unroll
  for(int i = 0; i < 4; ++i){
    int n = ty*4 + i;
    float v = t[tx][n];
    bf16_t h = (bf16_t)v;
    bf16_t l = (bf16_t)(v - (float)h);
    Th[(size_t)(n0 + n) * K + k0 + tx] = h;
    Tl[(size_t)(n0 + n) * K + k0 + tx] = l;
  }
}

// ---------------- merged projection GEMM: 2-MFMA form Ah*(Bh+Bl) ----------------

__global__ __launch_bounds__(256, 3) void gemm_proj_kernel(
    const float* __restrict__ Ar, const float* __restrict__ Ax,
    const bf16_t* __restrict__ Axb,
    const bf16_t* __restrict__ Weh, const bf16_t* __restrict__ Wel,
    const bf16_t* __restrict__ Wlh, const bf16_t* __restrict__ Wll,
    const bf16_t* __restrict__ Wrh, const bf16_t* __restrict__ Wrl,
    const float* __restrict__ biasL, const float* __restrict__ biasR,
    const float* __restrict__ biasB, float* __restrict__ ro,
    bf16_t* __restrict__ rpb, bf16_t* __restrict__ xlb, bf16_t* __restrict__ xrb,
    int R, int Nn, int rjobs, int xjobs, int bjobs){
  constexpr int LDA  = 136;
  constexpr int LDBB = 72;
  __shared__ char smem[53248];
  bf16_t* Ah  = (bf16_t*)smem;               // 34816
  bf16_t* Bhl = (bf16_t*)(smem + 34816);     // 18432

  const int tid  = threadIdx.x;
  const int lane = tid & 63;
  const int wid  = tid >> 6;
  const int wm = wid >> 1, wn = wid & 1;
  const int l15 = lane & 15;
  const int kb  = (lane >> 4) * 8;

  int nwg = gridDim.x;
  int lin = blockIdx.x;
  int w = ((nwg & 7) == 0) ? ((lin & 7) * (nwg >> 3) + (lin >> 3)) : lin;
  int job, jw;
  if(w < rjobs){ job = 0; jw = w; }
  else if(w < rjobs + xjobs){ job = 1; jw = w - rjobs; }
  else if(w < rjobs + 2 * xjobs){ job = 2; jw = w - rjobs - xjobs; }
  else { job = 3; jw = w - rjobs - 2 * xjobs; }

  if(job == 3){
    int idx8 = (jw * 256 + tid) * 8;
    if(idx8 < R * 128){
      const float* bp = biasB + (idx8 & 127);
      *(float4*)(ro + idx8)     = *(const float4*)bp;
      *(float4*)(ro + idx8 + 4) = *(const float4*)(bp + 4);
    }
    return;
  }

  const float*  A   = (job == 0) ? Ar : Ax;
  const bf16_t* Bth = (job == 0) ? Weh : (job == 1) ? Wlh : Wrh;
  const bf16_t* Btl = (job == 0) ? Wel : (job == 1) ? Wll : Wrl;
  const int M = (job == 0) ? R : Nn;
  const int row0 = (jw >> 3) * 128, col0 = (jw & 7) * 128;
  const bool abf = (job != 0) && (Axb != nullptr);

  const int ns0 = tid >> 2,        kq0 = tid & 3;
  const int ns1 = (tid + 256) >> 2, kq1 = (tid + 256) & 3;
  const size_t gb0 = (size_t)(col0 + ns0) * 128 + kq0 * 8;
  const size_t gb1 = (size_t)(col0 + ns1) * 128 + kq1 * 8;
  const int lo0 = ns0 * LDBB + kq0 * 8;
  const int lo1 = ns1 * LDBB + kq1 * 8;

  if(abf){
#pragma unroll
    for(int i = 0; i < 8; ++i){
      int f = tid + i * 256;
      int r = f >> 4, kq = f & 15;
      bf16x8 v = {};
      if(row0 + r < M) v = *(const bf16x8*)(Axb + (size_t)(row0 + r) * 128 + kq * 8);
      *(bf16x8*)&Ah[r * LDA + kq * 8] = v;
    }
  } else {
#pragma unroll
    for(int i = 0; i < 16; ++i){
      int f = tid + i * 256;
      int r = f >> 5, kq = f & 31;
      float4 v = make_float4(0.f, 0.f, 0.f, 0.f);
      if(row0 + r < M) v = *(const float4*)(A + (size_t)(row0 + r) * 128 + kq * 4);
      bf16x4 hv = (bf16x4){(bf16_t)v.x, (bf16_t)v.y, (bf16_t)v.z, (bf16_t)v.w};
      *(bf16x4*)&Ah[r * LDA + kq * 4] = hv;
    }
  }
  {
    bf16x8 h0 = *(const bf16x8*)(Bth + gb0);
    bf16x8 l0v = *(const bf16x8*)(Btl + gb0);
    bf16x8 h1 = *(const bf16x8*)(Bth + gb1);
    bf16x8 l1v = *(const bf16x8*)(Btl + gb1);
    *(bf16x8*)&Bhl[lo0]      = h0;
    *(bf16x8*)&Bhl[lo0 + 32] = l0v;
    *(bf16x8*)&Bhl[lo1]      = h1;
    *(bf16x8*)&Bhl[lo1 + 32] = l1v;
  }
  __syncthreads();

  f32x4 acc[4][4];
#pragma unroll
  for(int m = 0; m < 4; ++m)
#pragma unroll
    for(int n = 0; n < 4; ++n) acc[m][n] = (f32x4){0.f, 0.f, 0.f, 0.f};

  bf16x8 sb_h0, sb_l0, sb_h1, sb_l1;

#pragma unroll
  for(int step = 0; step < 4; ++step){
    const int k0 = step * 32;
    if(step < 3){
      sb_h0 = *(const bf16x8*)(Bth + gb0 + k0 + 32);
      sb_l0 = *(const bf16x8*)(Btl + gb0 + k0 + 32);
      sb_h1 = *(const bf16x8*)(Bth + gb1 + k0 + 32);
      sb_l1 = *(const bf16x8*)(Btl + gb1 + k0 + 32);
    }
    bf16x8 ah[4], bh[4], bl[4];
#pragma unroll
    for(int m = 0; m < 4; ++m){
      int r = wm * 64 + m * 16 + l15;
      ah[m] = *(bf16x8*)&Ah[r * LDA + k0 + kb];
    }
#pragma unroll
    for(int n = 0; n < 4; ++n){
      int c = wn * 64 + n * 16 + l15;
      bh[n] = *(bf16x8*)&Bhl[c * LDBB + kb];
      bl[n] = *(bf16x8*)&Bhl[c * LDBB + 32 + kb];
    }
#pragma unroll
    for(int m = 0; m < 4; ++m)
#pragma unroll
      for(int n = 0; n < 4; ++n){
        acc[m][n] = __builtin_amdgcn_mfma_f32_16x16x32_bf16(ah[m], bh[n], acc[m][n], 0, 0, 0);
        acc[m][n] = __builtin_amdgcn_mfma_f32_16x16x32_bf16(ah[m], bl[n], acc[m][n], 0, 0, 0);
      }
    if(step < 3){
      __syncthreads();
      *(bf16x8*)&Bhl[lo0]      = sb_h0;
      *(bf16x8*)&Bhl[lo0 + 32] = sb_l0;
      *(bf16x8*)&Bhl[lo1]      = sb_h1;
      *(bf16x8*)&Bhl[lo1 + 32] = sb_l1;
      __syncthreads();
    }
  }

  const float* biasP = (job == 0) ? nullptr : (job == 1) ? biasL : biasR;
  bf16_t* dst = (job == 0) ? rpb : (job == 1) ? xlb : xrb;
  bf16_t* tile = Ah;
  __syncthreads();
#pragma unroll
  for(int n = 0; n < 4; ++n){
    int col = wn * 64 + n * 16 + l15;
    float bv = biasP ? biasP[col0 + col] : 0.f;
#pragma unroll
    for(int m = 0; m < 4; ++m){
      int rb = wm * 64 + m * 16 + (lane >> 4) * 4;
#pragma unroll
      for(int r = 0; r < 4; ++r)
        tile[(rb + r) * 136 + col] = (bf16_t)(acc[m][n][r] + bv);
    }
  }
  __syncthreads();
#pragma unroll
  for(int i = 0; i < 8; ++i){
    int ei = i * 2048 + tid * 8;
    int rr = ei >> 7, cc = ei & 127;
    if(row0 + rr < M)
      *(bf16x8*)(dst + (size_t)(row0 + rr) * 1024 + col0 + cc) = *(bf16x8*)&tile[rr * 136 + cc];
  }
}

// ---------------- relation update GEMM: ro += relu(rpb) @ Wb (split-K 16, 2-MFMA) -------

__global__ __launch_bounds__(256) void gemm_rel_kernel(
    const bf16_t* __restrict__ Ag,
    const bf16_t* __restrict__ Bth, const bf16_t* __restrict__ Btl,
    float* __restrict__ C, int M){
  constexpr int LDK = 40;
  __shared__ bf16_t Ah[128 * LDK];
  __shared__ bf16_t Bh[128 * LDK];
  __shared__ bf16_t Bl[128 * LDK];

  const int tid  = threadIdx.x;
  const int lane = tid & 63;
  const int wid  = tid >> 6;
  const int wm = wid >> 1, wn = wid & 1;
  const int row0 = blockIdx.y * 128;
  const int l15 = lane & 15;
  const int kb  = (lane >> 4) * 8;
  const int kbeg = blockIdx.z * 64;

  f32x4 acc[4][4];
#pragma unroll
  for(int m = 0; m < 4; ++m)
#pragma unroll
    for(int n = 0; n < 4; ++n) acc[m][n] = (f32x4){0.f, 0.f, 0.f, 0.f};

#pragma unroll
  for(int tt = 0; tt < 2; ++tt){
    int k0 = kbeg + tt * 32;
    __syncthreads();
#pragma unroll
    for(int i = 0; i < 2; ++i){
      int f = tid + i * 256;
      int r = f >> 2, kq = f & 3;
      bf16x8 vh = {};
      if(row0 + r < M)
        vh = relu8(*(const bf16x8*)(Ag + (size_t)(row0 + r) * 1024 + k0 + kq * 8));
      *(bf16x8*)&Ah[r * LDK + kq * 8] = vh;
      size_t gb = (size_t)r * 1024 + k0 + kq * 8;
      *(bf16x8*)&Bh[r * LDK + kq * 8] = *(const bf16x8*)(Bth + gb);
      *(bf16x8*)&Bl[r * LDK + kq * 8] = *(const bf16x8*)(Btl + gb);
    }
    __syncthreads();

    bf16x8 ah[4], bh[4], bl[4];
#pragma unroll
    for(int m = 0; m < 4; ++m){
      int r = wm * 64 + m * 16 + l15;
      ah[m] = *(bf16x8*)&Ah[r * LDK + kb];
    }
#pragma unroll
    for(int n = 0; n < 4; ++n){
      int c = wn * 64 + n * 16 + l15;
      bh[n] = *(bf16x8*)&Bh[c * LDK + kb];
      bl[n] = *(bf16x8*)&Bl[c * LDK + kb];
    }
#pragma unroll
    for(int m = 0; m < 4; ++m)
#pragma unroll
      for(int n = 0; n < 4; ++n){
        acc[m][n] = __builtin_amdgcn_mfma_f32_16x16x32_bf16(ah[m], bh[n], acc[m][n], 0, 0, 0);
        acc[m][n] = __builtin_amdgcn_mfma_f32_16x16x32_bf16(ah[m], bl[n], acc[m][n], 0, 0, 0);
      }
  }

#pragma unroll
  for(int n = 0; n < 4; ++n){
    int col = wn * 64 + n * 16 + l15;
    if(col < 128){
#pragma unroll
      for(int m = 0; m < 4; ++m){
        int rbase = row0 + wm * 64 + m * 16 + (lane >> 4) * 4;
#pragma unroll
        for(int r = 0; r < 4; ++r){
          if(rbase + r < M)
            atomicAdd(&C[(size_t)(rbase + r) * 128 + col], acc[m][n][r]);
        }
      }
    }
  }
}

// ---------------- fused node kernel: 4 waves/node, EXACT-size batches ---------------
// R19 showed VALU-bound (67.7% busy) with 32% masked-duplicate waste
// (E[ceil(d/4)*4]/E[d] = 1.47 for Poisson(4)). Exact batches: unmasked 4-edge
// main loop (also drops mask fmas/selects), then exact 2-edge and 1-edge tails.

__global__ __launch_bounds__(256) void node_fused_kernel(
    const bf16_t* __restrict__ xlb, const bf16_t* __restrict__ xrb,
    const bf16_t* __restrict__ rpb,
    const int* __restrict__ offs, const int* __restrict__ srcs, const int* __restrict__ rels,
    const int* __restrict__ order,
    const float* __restrict__ att, const float* __restrict__ bias,
    float* __restrict__ xout, bf16_t* __restrict__ xq, int N){
  __shared__ float tsh[4][128];
  const int wid  = threadIdx.x >> 6;       // 0..3
  const int lane = threadIdx.x & 63;
  const int node = order[blockIdx.x];      // grid == N
  const int beg = offs[node], end = offs[node + 1];
  const float inv = 1.0f / fmaxf((float)(end - beg), 1.0f);

  const int o  = wid * 256 + lane * 4;
  const int h  = wid * 2 + (lane >> 5);
  const int c0 = (lane & 31) * 4;
  f32x4 av = *(const f32x4*)(att + h * 128 + c0);
  bf16x4 xrv = *(const bf16x4*)(xrb + (size_t)node * 1024 + o);
  f32x4 xr;
#pragma unroll
  for(int i = 0; i < 4; ++i) xr[i] = (float)xrv[i];

  f32x4 lac = (f32x4){0.f,0.f,0.f,0.f};
  f32x4 num = (f32x4){0.f,0.f,0.f,0.f};
  float m = -INFINITY, den = 0.f;

  int p = beg;
  // ---- full 4-edge batches (no masks, no duplicate work) ----
  for(; p + 4 <= end; p += 4){
    int s0 = srcs[p],   r0 = rels[p];
    int s1 = srcs[p+1], r1 = rels[p+1];
    int s2 = srcs[p+2], r2 = rels[p+2];
    int s3 = srcs[p+3], r3 = rels[p+3];
    bf16x4 a0 = *(const bf16x4*)(xlb + (size_t)s0 * 1024 + o);
    bf16x4 b0 = *(const bf16x4*)(rpb + (size_t)r0 * 1024 + o);
    bf16x4 a1 = *(const bf16x4*)(xlb + (size_t)s1 * 1024 + o);
    bf16x4 b1 = *(const bf16x4*)(rpb + (size_t)r1 * 1024 + o);
    bf16x4 a2 = *(const bf16x4*)(xlb + (size_t)s2 * 1024 + o);
    bf16x4 b2 = *(const bf16x4*)(rpb + (size_t)r2 * 1024 + o);
    bf16x4 a3 = *(const bf16x4*)(xlb + (size_t)s3 * 1024 + o);
    bf16x4 b3 = *(const bf16x4*)(rpb + (size_t)r3 * 1024 + o);
    float l0 = 0.f, l1 = 0.f, l2 = 0.f, l3 = 0.f;
#pragma unroll
    for(int i = 0; i < 4; ++i){
      float v0 = (float)b0[i], v1 = (float)b1[i], v2 = (float)b2[i], v3 = (float)b3[i];
      lac[i] += (v0 + v1) + (v2 + v3);
      l0 += leaky((float)a0[i] + xr[i] + v0) * av[i];
      l1 += leaky((float)a1[i] + xr[i] + v1) * av[i];
      l2 += leaky((float)a2[i] + xr[i] + v2) * av[i];
      l3 += leaky((float)a3[i] + xr[i] + v3) * av[i];
    }
#pragma unroll
    for(int q = 16; q >= 1; q >>= 1){
      l0 += __shfl_xor(l0, q); l1 += __shfl_xor(l1, q);
      l2 += __shfl_xor(l2, q); l3 += __shfl_xor(l3, q);
    }
    float nm = fmaxf(m, fmaxf(fmaxf(l0, l1), fmaxf(l2, l3)));
    float sc = __expf(m - nm);
    float w0 = __expf(l0 - nm), w1 = __expf(l1 - nm);
    float w2 = __expf(l2 - nm), w3 = __expf(l3 - nm);
    den = den * sc + ((w0 + w1) + (w2 + w3));
#pragma unroll
    for(int i = 0; i < 4; ++i)
      num[i] = num[i] * sc + w0 * (float)a0[i] + w1 * (float)a1[i]
                           + w2 * (float)a2[i] + w3 * (float)a3[i];
    m = nm;
  }
  // ---- exact 2-edge tail ----
  if(p + 2 <= end){
    int s0 = srcs[p],   r0 = rels[p];
    int s1 = srcs[p+1], r1 = rels[p+1];
    bf16x4 a0 = *(const bf16x4*)(xlb + (size_t)s0 * 1024 + o);
    bf16x4 b0 = *(const bf16x4*)(rpb + (size_t)r0 * 1024 + o);
    bf16x4 a1 = *(const bf16x4*)(xlb + (size_t)s1 * 1024 + o);
    bf16x4 b1 = *(const bf16x4*)(rpb + (size_t)r1 * 1024 + o);
    float l0 = 0.f, l1 = 0.f;
#pragma unroll
    for(int i = 0; i < 4; ++i){
      float v0 = (float)b0[i], v1 = (float)b1[i];
      lac[i] += v0 + v1;
      l0 += leaky((float)a0[i] + xr[i] + v0) * av[i];
      l1 += leaky((float)a1[i] + xr[i] + v1) * av[i];
    }
#pragma unroll
    for(int q = 16; q >= 1; q >>= 1){
      l0 += __shfl_xor(l0, q); l1 += __shfl_xor(l1, q);
    }
    float nm = fmaxf(m, fmaxf(l0, l1));
    float sc = __expf(m - nm);
    float w0 = __expf(l0 - nm), w1 = __expf(l1 - nm);
    den = den * sc + w0 + w1;
#pragma unroll
    for(int i = 0; i < 4; ++i)
      num[i] = num[i] * sc + w0 * (float)a0[i] + w1 * (float)a1[i];
    m = nm;
    p += 2;
  }
  // ---- exact 1-edge tail ----
  if(p < end){
    int s0 = srcs[p], r0 = rels[p];
    bf16x4 a0 = *(const bf16x4*)(xlb + (size_t)s0 * 1024 + o);
    bf16x4 b0 = *(const bf16x4*)(rpb + (size_t)r0 * 1024 + o);
    float l0 = 0.f;
#pragma unroll
    for(int i = 0; i < 4; ++i){
      float v0 = (float)b0[i];
      lac[i] += v0;
      l0 += leaky((float)a0[i] + xr[i] + v0) * av[i];
    }
#pragma unroll
    for(int q = 16; q >= 1; q >>= 1) l0 += __shfl_xor(l0, q);
    float nm = fmaxf(m, l0);
    float sc = __expf(m - nm), w0 = __expf(l0 - nm);
    den = den * sc + w0;
#pragma unroll
    for(int i = 0; i < 4; ++i) num[i] = num[i] * sc + w0 * (float)a0[i];
    m = nm;
  }

  // self loop: edge_attr = mean of incoming rproj; self message = own xl row
  bf16x4 xlv = *(const bf16x4*)(xlb + (size_t)node * 1024 + o);
  float sl = 0.f;
#pragma unroll
  for(int i = 0; i < 4; ++i)
    sl += leaky((float)xlv[i] + xr[i] + lac[i] * inv) * av[i];
#pragma unroll
  for(int q = 16; q >= 1; q >>= 1) sl += __shfl_xor(sl, q);
  {
    float nm = fmaxf(m, sl);
    float sc = __expf(m - nm), wv = __expf(sl - nm);
    den = den * sc + wv;
#pragma unroll
    for(int i = 0; i < 4; ++i) num[i] = num[i] * sc + wv * (float)xlv[i];
    m = nm;
  }

  // per-head normalize; combine the wave's two heads (lane ^ 32), then 4-wave LDS sum
  f32x4 t;
  float d = 1.0f / den;
#pragma unroll
  for(int i = 0; i < 4; ++i) t[i] = num[i] * d;
#pragma unroll
  for(int i = 0; i < 4; ++i) t[i] += __shfl_xor(t[i], 32);

  if(lane < 32){
#pragma unroll
    for(int i = 0; i < 4; ++i) tsh[wid][lane * 4 + i] = t[i];
  }
  __syncthreads();
  if(wid == 0 && lane < 32){
    const float* bp = bias + lane * 4;
    float q[4];
#pragma unroll
    for(int i = 0; i < 4; ++i){
      int c = lane * 4 + i;
      q[i] = (tsh[0][c] + tsh[1][c] + tsh[2][c] + tsh[3][c]) * 0.125f + bp[i];
    }
    bf16x4 qb;
#pragma unroll
    for(int i = 0; i < 4; ++i) qb[i] = (bf16_t)q[i];
    *(bf16x4*)(xq + (size_t)node * 128 + lane * 4) = qb;
    if(xout){
      *(float4*)(xout + (size_t)node * 128 + lane * 4) = make_float4(q[0], q[1], q[2], q[3]);
    }
  }
}

// ---------------- launch ----------------

extern "C" void kernel_launch(void* const* d_in, const int* in_sizes, int n_in,
                              void* d_out, int out_size, void* d_ws, size_t ws_size,
                              hipStream_t stream){
  const float* x0   = (const float*)d_in[0];
  const int*   ei   = (const int*)d_in[1];
  const float* rel0 = (const float*)d_in[2];
  const int*   ridx = (const int*)d_in[3];
  const float* Wl   = (const float*)d_in[4];
  const float* bl   = (const float*)d_in[5];
  const float* Wr   = (const float*)d_in[6];
  const float* br   = (const float*)d_in[7];
  const float* We   = (const float*)d_in[8];
  const float* att  = (const float*)d_in[9];
  const float* bias = (const float*)d_in[10];
  const float* Wb   = (const float*)d_in[11];
  const float* bb   = (const float*)d_in[12];

  const int D = 128, HC = 1024;
  const int N = in_sizes[0] / D;
  const int E = in_sizes[1] / 2;
  const int R = in_sizes[2] / D;
  const int WSZ = D * HC;
  const int NB = (N + 255) / 256;
  const int SCB = (E + 255) / 256;

  const int* src = ei;
  const int* dst = ei + E;

  char* ws = (char*)d_ws;
  size_t off = 0;
  auto alloc = [&](size_t bytes) -> void* {
    void* p = ws + off;
    off += (bytes + 255) & ~(size_t)255;
    return p;
  };
  bf16_t* xlb    = (bf16_t*)alloc((size_t)N * HC * 2);
  bf16_t* xrb    = (bf16_t*)alloc((size_t)N * HC * 2);
  bf16_t* rpb    = (bf16_t*)alloc((size_t)R * HC * 2);
  bf16_t* xqA    = (bf16_t*)alloc((size_t)N * D * 2);
  bf16_t* xqB    = (bf16_t*)alloc((size_t)N * D * 2);
  float*  rbufA  = (float*)alloc((size_t)R * D * 4);
  float*  rbufB  = (float*)alloc((size_t)R * D * 4);
  int* zbase   = (int*)alloc((size_t)(2 * N) * 4);
  int* deg     = zbase;
  int* cursor  = zbase + N;
  int* offs    = (int*)alloc((size_t)(N + 1) * 4);
  int* blkhist = (int*)alloc((size_t)NB * 256 * 4);
  int* order   = (int*)alloc((size_t)N * 4);
  int* srcs    = (int*)alloc((size_t)E * 4);
  int* rels    = (int*)alloc((size_t)E * 4);
  bf16_t* tWl_h = (bf16_t*)alloc((size_t)N_LAYERS * WSZ * 2);
  bf16_t* tWl_l = (bf16_t*)alloc((size_t)N_LAYERS * WSZ * 2);
  bf16_t* tWr_h = (bf16_t*)alloc((size_t)N_LAYERS * WSZ * 2);
  bf16_t* tWr_l = (bf16_t*)alloc((size_t)N_LAYERS * WSZ * 2);
  bf16_t* tWe_h = (bf16_t*)alloc((size_t)N_LAYERS * WSZ * 2);
  bf16_t* tWe_l = (bf16_t*)alloc((size_t)N_LAYERS * WSZ * 2);
  bf16_t* tWb_h = (bf16_t*)alloc((size_t)N_LAYERS * WSZ * 2);
  bf16_t* tWb_l = (bf16_t*)alloc((size_t)N_LAYERS * WSZ * 2);
  bf16_t* xq[2] = {xqA, xqB};
  float* rbuf[2] = {rbufA, rbufB};

  float* out_x = (float*)d_out;
  float* out_r = (float*)d_out + (size_t)N * D;

  // CSR build + degree-descending order
  fill_int_kernel<<<(2 * N + 255) / 256, 256, 0, stream>>>(zbase, 0, 2 * N);
  hist_kernel<<<(E + 255) / 256, 256, 0, stream>>>(dst, E, deg);
  scan_kernel<<<1, 256, 0, stream>>>(deg, offs, N);
  scatter_bhist_kernel<<<SCB + NB, 256, 0, stream>>>(
      src, dst, ridx, E, offs, cursor, srcs, rels, N, blkhist, SCB);
  deg_base_kernel<<<1, 256, 0, stream>>>(blkhist, NB);
  deg_place_kernel<<<NB, 256, 0, stream>>>(offs, N, blkhist, order);

  // weight prep: all 16 transpose+splits in ONE dispatch
  transpose_split_all_kernel<<<dim3(128, 1, 16), dim3(32, 8), 0, stream>>>(
      Wl, Wr, We, Wb, tWl_h, tWl_l, tWr_h, tWr_l, tWe_h, tWe_l, tWb_h, tWb_l);

  const int rjobs = ((R + 127) / 128) * (HC / 128);
  const int xjobs = ((N + 127) / 128) * (HC / 128);
  const int bjobs = 128;
  const int nwg = rjobs + 2 * xjobs + bjobs;   // 1520, %8 == 0

  for(int l = 0; l < N_LAYERS; ++l){
    const bf16_t* xq_in = (l == 0) ? nullptr : xq[(l + 1) & 1];
    bf16_t*       xq_out = xq[l & 1];
    float*        xo  = (l == N_LAYERS - 1) ? out_x : nullptr;
    const float*  rin = (l == 0) ? rel0 : rbuf[(l + 1) & 1];
    float*        ro  = (l == N_LAYERS - 1) ? out_r : rbuf[l & 1];
    size_t wo = (size_t)l * WSZ;
    const float* bl_l  = bl + (size_t)l * HC;
    const float* br_l  = br + (size_t)l * HC;
    const float* att_l = att + (size_t)l * 8 * 128;
    const float* bias_l= bias + (size_t)l * D;
    const float* bb_l  = bb + (size_t)l * D;

    // merged projections + bias prefill (2-MFMA; A-once + B-stage split)
    gemm_proj_kernel<<<nwg, 256, 0, stream>>>(
        rin, x0, xq_in, tWe_h + wo, tWe_l + wo, tWl_h + wo, tWl_l + wo, tWr_h + wo, tWr_l + wo,
        bl_l, br_l, bb_l, ro, rpb, xlb, xrb, R, N, rjobs, xjobs, bjobs);
    // fused node pass: 4 waves/node, exact-size batches (VALU-bound fix)
    node_fused_kernel<<<N, 256, 0, stream>>>(
        xlb, xrb, rpb, offs, srcs, rels, order, att_l, bias_l, xo, xq_out, N);
    // relation update: ro += relu(rpb) @ Wb, split-K 16
    gemm_rel_kernel<<<dim3(1, (R + 127) / 128, 16), 256, 0, stream>>>(
        rpb, tWb_h + wo, tWb_l + wo, ro, R);
  }
}